// Round 10
// baseline (77.832 us; speedup 1.0000x reference)
//
#include <hip/hip_runtime.h>

#define Bx 16
#define Gx 128
#define Nx 512
#define Px 4
#define Kx 3
#define Fx 128
#define NEG_SLOPE 0.2f
#define ZERO_TOL 1e-9f
#define BIGF 1.0e30f

typedef unsigned short u16;
typedef unsigned int u32;
typedef unsigned long long u64;
typedef __bf16 v8bf __attribute__((ext_vector_type(8)));
typedef _Float16 v8hf __attribute__((ext_vector_type(8)));
typedef float v4f __attribute__((ext_vector_type(4)));

__device__ __forceinline__ u16 f2b(float f) {
  union { float f; u32 u; } v; v.f = f;
  u32 r = (v.u + 0x7fffu + ((v.u >> 16) & 1u)) >> 16;
  return (u16)r;
}
__device__ __forceinline__ u16 f2h(float f) {
  union { _Float16 h; u16 u; } v; v.h = (_Float16)f;
  return v.u;
}

// async global->LDS, 16B per lane; LDS dst must be wave-uniform base (+lane*16)
#define G2L16(gsrc, ldst)                                                     \
  __builtin_amdgcn_global_load_lds(                                           \
      (const __attribute__((address_space(1))) void*)(gsrc),                  \
      (__attribute__((address_space(3))) void*)(ldst), 16, 0, 0)

// ---------------------------------------------------------------------------
// prep: fused {mask(ballot) | castx3 | castw16 | casth} by block range.
// blocks: [0,512) mask, [512,1536) castx3, [1536,1600) castw16, [1600,1792) casth
// ---------------------------------------------------------------------------
__global__ __launch_bounds__(256) void prep_kernel(const float* __restrict__ S,
                                                   const float* __restrict__ x,
                                                   const float* __restrict__ W,
                                                   const float* __restrict__ h,
                                                   u32* __restrict__ mb,
                                                   u16* __restrict__ xb,
                                                   u16* __restrict__ xTb,
                                                   u16* __restrict__ xT16,
                                                   u16* __restrict__ w16,
                                                   u16* __restrict__ Hb) {
  const int blk = blockIdx.x;
  const int tid = threadIdx.x;
  __shared__ float t[32][33];
  if (blk < 512) {
    // mask via ballot: block covers floats [blk*8192, blk*8192+8192)
    const int w = tid >> 6, l = tid & 63;
    const size_t base = (size_t)blk * 8192;
#pragma unroll 4
    for (int i = 0; i < 32; i++) {
      float v = S[base + i * 256 + tid];
      u64 m = __ballot(fabsf(v) > ZERO_TOL);
      if (l == 0) *(u64*)&mb[(base + i * 256 + w * 64) >> 5] = m;
    }
  } else if (blk < 1536) {
    const int idx = blk - 512;
    const int b = idx >> 6, g0 = ((idx >> 4) & 3) * 32, n0 = (idx & 15) * 32;
    const int r = tid >> 3, c4 = (tid & 7) * 4;
    const float* xp = x + (size_t)b * Gx * Nx;
    float4 v = *(const float4*)&xp[(g0 + r) * Nx + n0 + c4];
    ushort4 o;
    o.x = f2b(v.x); o.y = f2b(v.y); o.z = f2b(v.z); o.w = f2b(v.w);
    *(ushort4*)&xb[(size_t)b * Gx * Nx + (g0 + r) * Nx + n0 + c4] = o;
    t[r][c4 + 0] = v.x; t[r][c4 + 1] = v.y; t[r][c4 + 2] = v.z; t[r][c4 + 3] = v.w;
    __syncthreads();
    float tv[4] = {t[c4 + 0][r], t[c4 + 1][r], t[c4 + 2][r], t[c4 + 3][r]};
    ushort4 ob, oh;
    ob.x = f2b(tv[0]); oh.x = f2h(tv[0]);
    ob.y = f2b(tv[1]); oh.y = f2h(tv[1]);
    ob.z = f2b(tv[2]); oh.z = f2h(tv[2]);
    ob.w = f2b(tv[3]); oh.w = f2h(tv[3]);
    size_t off = (size_t)b * Nx * Gx + (size_t)(n0 + r) * Gx + g0 + c4;
    *(ushort4*)&xTb[off] = ob;
    *(ushort4*)&xT16[off] = oh;
  } else if (blk < 1600) {
    int i4 = ((blk - 1536) * 256 + tid) * 4;
    float4 v = *(const float4*)&W[i4];
    ushort4 o;
    o.x = f2h(v.x); o.y = f2h(v.y); o.z = f2h(v.z); o.w = f2h(v.w);
    *(ushort4*)&w16[i4] = o;
  } else {
    int i4 = ((blk - 1600) * 256 + tid) * 4;
    float4 v = *(const float4*)&h[i4];
    ushort4 o;
    o.x = f2b(v.x); o.y = f2b(v.y); o.z = f2b(v.z); o.w = f2b(v.w);
    *(ushort4*)&Hb[i4] = o;
  }
}

// ---------------------------------------------------------------------------
// wxt16: WxT[n][g] = sum_h xT[n][h] * W[g][h]  (fp16 MFMA, unchanged r6-verified)
// ---------------------------------------------------------------------------
__global__ __launch_bounds__(256) void wxt16_kernel(const u16* __restrict__ xT16,
                                                    const u16* __restrict__ w16,
                                                    u16* __restrict__ WxT16) {
  __shared__ __align__(16) char smem[49152];
  constexpr int OB = 16384;
  const int bp = blockIdx.x, b = bp >> 2, p = bp & 3;
  const int rt = blockIdx.y;
  const int tid = threadIdx.x;
  const int w = tid >> 6, l = tid & 63;
  const int wr = w >> 1, wc = w & 1;
  const int lr = l & 15, ks = l >> 4;

  const u16* Ap = xT16 + ((size_t)b * Nx + rt * 64) * Gx;
  const u16* Bp = w16 + (size_t)p * Gx * Gx;
#pragma unroll
  for (int it = 0; it < 4; it++) {
    int chunk = it * 256 + w * 64 + l;
    int r = chunk >> 4, kq = l & 15;
    int kg = (kq ^ (r & 15)) * 8;
    G2L16(Ap + (size_t)r * Gx + kg, smem + it * 4096 + w * 1024);
  }
#pragma unroll
  for (int it = 0; it < 8; it++) {
    int chunk = it * 256 + w * 64 + l;
    int r = chunk >> 4, kq = l & 15;
    int kg = (kq ^ (r & 15)) * 8;
    G2L16(Bp + (size_t)r * Gx + kg, smem + OB + it * 4096 + w * 1024);
  }
  __syncthreads();

  v4f acc[2][4];
#pragma unroll
  for (int fr = 0; fr < 2; fr++)
#pragma unroll
    for (int fc = 0; fc < 4; fc++) acc[fr][fc] = (v4f){0.f, 0.f, 0.f, 0.f};

#pragma unroll
  for (int t = 0; t < 4; t++) {
    int kk = t * 4 + ks;
    v8hf ah[2];
#pragma unroll
    for (int fr = 0; fr < 2; fr++) {
      int ra = wr * 32 + fr * 16 + lr;
      ah[fr] = *(const v8hf*)(smem + ra * 256 + ((kk ^ (ra & 15)) * 16));
    }
#pragma unroll
    for (int fc = 0; fc < 4; fc++) {
      int rb = wc * 64 + fc * 16 + lr;
      v8hf bh = *(const v8hf*)(smem + OB + rb * 256 + ((kk ^ (rb & 15)) * 16));
#pragma unroll
      for (int fr = 0; fr < 2; fr++)
        acc[fr][fc] = __builtin_amdgcn_mfma_f32_16x16x32_f16(ah[fr], bh, acc[fr][fc], 0, 0, 0);
    }
  }

  u16* op = WxT16 + (size_t)bp * Nx * Gx;
#pragma unroll
  for (int fr = 0; fr < 2; fr++)
#pragma unroll
    for (int fc = 0; fc < 4; fc++) {
      int n = rt * 64 + wr * 32 + fr * 16 + ks * 4;
      int g = wc * 64 + fc * 16 + lr;
#pragma unroll
      for (int q = 0; q < 4; q++) op[(size_t)(n + q) * Gx + g] = f2h(acc[fr][fc][q]);
    }
}

// ---------------------------------------------------------------------------
// attn7: attn4 math with A-in-regs (r8-proven) + SINGLE 32KB B buffer.
// LDS 38912 -> 4 blocks/CU (32 waves/CU) for 2x latency hiding.
// grid (B*P, N/64), 512 thr (2 wr x 4 wc waves). Block: 64 i x 512 j, K=128.
// ---------------------------------------------------------------------------
__global__ __launch_bounds__(512, 4) void attn7_kernel(const u16* __restrict__ xT16,
                                                       const u16* __restrict__ WxT16,
                                                       const u32* __restrict__ mb,
                                                       u16* __restrict__ aijT) {
  __shared__ __align__(16) char smem[38912];  // B 32K (A overlay) | mask 4K | red 2K
  constexpr int OMBS = 32768, ORED = 36864;
  const int bp = blockIdx.x, b = bp >> 2;
  const int i0 = blockIdx.y * 64;
  const int tid = threadIdx.x;
  const int w = tid >> 6, l = tid & 63;
  const int wr = w >> 2, wc = w & 3;
  const int lr = l & 15, ks = l >> 4;

  {  // mask rows -> LDS (64 rows x 16 words)
    const u32* mbp = mb + ((size_t)b * Nx + i0) * 16;
    u32* mbs = (u32*)(smem + OMBS);
    mbs[tid] = mbp[tid];
    mbs[tid + 512] = mbp[tid + 512];
  }
  {  // stage A (16 KB) into smem[0..16384), chunk-XOR (r&15)
    const u16* Ap = xT16 + ((size_t)b * Nx + i0) * Gx;
#pragma unroll
    for (int it = 0; it < 2; it++) {
      int chunk = it * 512 + w * 64 + l;
      int r = chunk >> 4, kq = l & 15;
      int kg = (kq ^ (r & 15)) * 8;
      G2L16(Ap + (size_t)r * Gx + kg, smem + it * 8192 + w * 1024);
    }
  }
  __syncthreads();  // A + mask landed

  // A -> registers: areg[fr][t], kk = t*4 + ks
  v8hf areg[2][4];
#pragma unroll
  for (int fr = 0; fr < 2; fr++) {
    int ra = wr * 32 + fr * 16 + lr;
#pragma unroll
    for (int t = 0; t < 4; t++) {
      int kk = t * 4 + ks;
      areg[fr][t] = *(const v8hf*)(smem + ra * 256 + ((kk ^ (ra & 15)) * 16));
    }
  }
  __syncthreads();  // all waves done reading A (B overlays it)

  v4f acc[2][8];
#pragma unroll
  for (int fr = 0; fr < 2; fr++)
#pragma unroll
    for (int fc = 0; fc < 8; fc++) acc[fr][fc] = (v4f){0.f, 0.f, 0.f, 0.f};

  const u16* Bp = WxT16 + (size_t)bp * Nx * Gx;
  for (int t = 0; t < 4; t++) {
    int g0 = t * 32;
#pragma unroll
    for (int it = 0; it < 4; it++) {
      int chunk = it * 512 + w * 64 + l;
      int r = chunk >> 2, kq = l & 3;
      int kg = (kq ^ (r & 3)) * 8;
      G2L16(Bp + (size_t)r * Gx + g0 + kg, smem + it * 8192 + w * 1024);
    }
    __syncthreads();  // B_t landed
#pragma unroll
    for (int fc = 0; fc < 8; fc++) {
      int rb = wc * 128 + fc * 16 + lr;
      v8hf bh = *(const v8hf*)(smem + rb * 64 + ((ks ^ (rb & 3)) * 16));
#pragma unroll
      for (int fr = 0; fr < 2; fr++)
        acc[fr][fc] = __builtin_amdgcn_mfma_f32_16x16x32_f16(areg[fr][t], bh, acc[fr][fc], 0, 0, 0);
    }
    __syncthreads();  // all waves done reading B_t before overwrite
  }

  u32* mbs = (u32*)(smem + OMBS);
  float* red0 = (float*)(smem + ORED);
  float* red1 = red0 + 256;

  // pass 1: masked leaky-relu + cross-wave row max partials
#pragma unroll
  for (int fr = 0; fr < 2; fr++)
#pragma unroll
    for (int q = 0; q < 4; q++) {
      int row = wr * 32 + fr * 16 + ks * 4 + q;
      float m = -BIGF;
#pragma unroll
      for (int fc = 0; fc < 8; fc++) {
        u32 word = mbs[row * 16 + wc * 4 + (fc >> 1)];
        int bit = ((fc & 1) << 4) + lr;
        float v = acc[fr][fc][q];
        v = v >= 0.f ? v : NEG_SLOPE * v;
        v = ((word >> bit) & 1u) ? v : -BIGF;
        acc[fr][fc][q] = v;
        m = fmaxf(m, v);
      }
      m = fmaxf(m, __shfl_xor(m, 1, 64));
      m = fmaxf(m, __shfl_xor(m, 2, 64));
      m = fmaxf(m, __shfl_xor(m, 4, 64));
      m = fmaxf(m, __shfl_xor(m, 8, 64));
      if (lr == 0) red0[row * 4 + wc] = m;
    }
  __syncthreads();
  // pass 2: global max, exp, cross-wave row sum partials
#pragma unroll
  for (int fr = 0; fr < 2; fr++)
#pragma unroll
    for (int q = 0; q < 4; q++) {
      int row = wr * 32 + fr * 16 + ks * 4 + q;
      float4 pm = *(const float4*)&red0[row * 4];
      float gm = fmaxf(fmaxf(pm.x, pm.y), fmaxf(pm.z, pm.w));
      float s = 0.f;
#pragma unroll
      for (int fc = 0; fc < 8; fc++) {
        float v = acc[fr][fc][q];
        float e = (v <= -0.5f * BIGF) ? 0.f : __expf(v - gm);
        acc[fr][fc][q] = e;
        s += e;
      }
      s += __shfl_xor(s, 1, 64);
      s += __shfl_xor(s, 2, 64);
      s += __shfl_xor(s, 4, 64);
      s += __shfl_xor(s, 8, 64);
      if (lr == 0) red1[row * 4 + wc] = s;
    }
  __syncthreads();
  // pass 3: normalize + direct ushort4 stores (4 consecutive i per lane)
  u16* dst = aijT + (size_t)bp * Nx * Nx + i0;
#pragma unroll
  for (int fr = 0; fr < 2; fr++) {
    int rbase = wr * 32 + fr * 16 + ks * 4;
    float inv[4];
#pragma unroll
    for (int q = 0; q < 4; q++) {
      float4 ps = *(const float4*)&red1[(rbase + q) * 4];
      float tot = (ps.x + ps.y) + (ps.z + ps.w);
      inv[q] = tot > 0.f ? 1.f / tot : 0.f;
    }
#pragma unroll
    for (int fc = 0; fc < 8; fc++) {
      int j = wc * 128 + fc * 16 + lr;
      ushort4 pk;
      pk.x = f2b(acc[fr][fc][0] * inv[0]);
      pk.y = f2b(acc[fr][fc][1] * inv[1]);
      pk.z = f2b(acc[fr][fc][2] * inv[2]);
      pk.w = f2b(acc[fr][fc][3] * inv[3]);
      *(ushort4*)&dst[(size_t)j * Nx + rbase] = pk;
    }
  }
}

// ---------------------------------------------------------------------------
// gnt MODE 0 (r7-verified): hop1  A=aijT(bp)  B=xb(b) -> z1[g][m] + z1T[m][g]
// 2-phase double-buffered, one barrier per K-iter.
// ---------------------------------------------------------------------------
__global__ __launch_bounds__(256) void hop1_kernel(const u16* __restrict__ pA,
                                                   const u16* __restrict__ pB,
                                                   u16* __restrict__ o1,
                                                   u16* __restrict__ o2) {
  __shared__ __align__(16) char smem[2][12288];
  const int bp = blockIdx.x;
  const int b = bp >> 2;
  const int rt = blockIdx.y;
  const int tid = threadIdx.x;
  const int w = tid >> 6, l = tid & 63;
  const int wr = w >> 1, wc = w & 1;
  const int lr = l & 15, kslot = l >> 4;

  const u16* Abase = pA + (size_t)bp * Nx * Nx + (size_t)rt * 64 * Nx;
  const u16* Bbase = pB + (size_t)b * Gx * Nx;

  const int sar = tid >> 2;
  const int sakg = (tid & 3) ^ (sar & 3);
  const int sbr0 = tid >> 2, sbkg0 = (tid & 3) ^ (sbr0 & 3);
  const int sbr1 = (tid + 256) >> 2, sbkg1 = (tid & 3) ^ (sbr1 & 3);

  int aoff[2], boff[4];
#pragma unroll
  for (int fr = 0; fr < 2; fr++) {
    int row = wr * 32 + fr * 16 + lr;
    aoff[fr] = row * 64 + ((kslot ^ (row & 3)) * 16);
  }
#pragma unroll
  for (int fc = 0; fc < 4; fc++) {
    int row = wc * 64 + fc * 16 + lr;
    boff[fc] = 4096 + row * 64 + ((kslot ^ (row & 3)) * 16);
  }

  auto STAGE = [&](int bufi, int k0) {
    char* base = smem[bufi];
    G2L16(Abase + (size_t)sar * Nx + k0 + sakg * 8, base + w * 1024);
    G2L16(Bbase + (size_t)sbr0 * Nx + k0 + sbkg0 * 8, base + 4096 + w * 1024);
    G2L16(Bbase + (size_t)sbr1 * Nx + k0 + sbkg1 * 8, base + 8192 + w * 1024);
  };

  v4f acc[2][4];
#pragma unroll
  for (int fr = 0; fr < 2; fr++)
#pragma unroll
    for (int fc = 0; fc < 4; fc++) acc[fr][fc] = (v4f){0.f, 0.f, 0.f, 0.f};

  STAGE(0, 0);
  int cur = 0;
  for (int t = 0; t < 16; t++) {
    __syncthreads();
    if (t + 1 < 16) STAGE(cur ^ 1, (t + 1) * 32);
    const char* bb = smem[cur];
    v8bf af[2], bf4[4];
#pragma unroll
    for (int fr = 0; fr < 2; fr++) af[fr] = *(const v8bf*)(bb + aoff[fr]);
#pragma unroll
    for (int fc = 0; fc < 4; fc++) bf4[fc] = *(const v8bf*)(bb + boff[fc]);
#pragma unroll
    for (int fr = 0; fr < 2; fr++)
#pragma unroll
      for (int fc = 0; fc < 4; fc++)
        acc[fr][fc] = __builtin_amdgcn_mfma_f32_16x16x32_bf16(af[fr], bf4[fc],
                                                              acc[fr][fc], 0, 0, 0);
    cur ^= 1;
  }

  u16* z1p = o1 + (size_t)bp * Gx * Nx;
  u16* z1Tp = o2 + (size_t)bp * Nx * Gx;
#pragma unroll
  for (int fr = 0; fr < 2; fr++)
#pragma unroll
    for (int fc = 0; fc < 4; fc++) {
      int m0 = rt * 64 + wr * 32 + fr * 16 + kslot * 4;
      int g = wc * 64 + fc * 16 + lr;
      v4f a = acc[fr][fc];
      ushort4 pk;
      pk.x = f2b(a[0]); pk.y = f2b(a[1]); pk.z = f2b(a[2]); pk.w = f2b(a[3]);
      *(ushort4*)&z1p[(size_t)g * Nx + m0] = pk;
      z1Tp[(size_t)(m0 + 0) * Gx + g] = pk.x;
      z1Tp[(size_t)(m0 + 1) * Gx + g] = pk.y;
      z1Tp[(size_t)(m0 + 2) * Gx + g] = pk.z;
      z1Tp[(size_t)(m0 + 3) * Gx + g] = pk.w;
    }
}

// ---------------------------------------------------------------------------
// hop2filt: fused hop2 + filt per (bp, m'-tile of 64).
// Phase 1 (= gnt template, A/B roles swapped): z2T_tile[m'loc][g] =
//   sum_m aijT[m'][m]*z1[g][m]  -> bf16 into swizzled LDS tile [64][128].
// Phase 2 (= MODE2 with seg2 A from LDS tile): out[f][n=m'] =
//   relu(sum_kg H[f][kg]*{xTb,z1T,tile}[m'][kg] + bias[f]).
// LDS 40960 (2x12288 staging + 16384 tile).
// ---------------------------------------------------------------------------
__global__ __launch_bounds__(256) void hop2filt_kernel(const u16* __restrict__ aijT,
                                                       const u16* __restrict__ z1,
                                                       const u16* __restrict__ z1T,
                                                       const u16* __restrict__ xTb,
                                                       const u16* __restrict__ Hb,
                                                       const float* __restrict__ bias,
                                                       float* __restrict__ out) {
  __shared__ __align__(16) char smem[2 * 12288 + 16384];
  constexpr int OT = 24576;  // z2 tile offset
  const int bp = blockIdx.x, b = bp >> 2, p = bp & 3;
  const int rt = blockIdx.y;  // m'-tile (8 x 64 rows)
  const int tid = threadIdx.x;
  const int w = tid >> 6, l = tid & 63;
  const int wr = w >> 1, wc = w & 1;
  const int lr = l & 15, kslot = l >> 4;

  const int sar = tid >> 2;
  const int sakg = (tid & 3) ^ (sar & 3);
  const int sbr0 = tid >> 2, sbkg0 = (tid & 3) ^ (sbr0 & 3);
  const int sbr1 = (tid + 256) >> 2, sbkg1 = (tid & 3) ^ (sbr1 & 3);

  int aoff[2], boff[4];
#pragma unroll
  for (int fr = 0; fr < 2; fr++) {
    int row = wr * 32 + fr * 16 + lr;
    aoff[fr] = row * 64 + ((kslot ^ (row & 3)) * 16);
  }
#pragma unroll
  for (int fc = 0; fc < 4; fc++) {
    int row = wc * 64 + fc * 16 + lr;
    boff[fc] = 4096 + row * 64 + ((kslot ^ (row & 3)) * 16);
  }

  // ---------------- phase 1: z2 tile ----------------
  const u16* A1 = aijT + (size_t)bp * Nx * Nx + (size_t)rt * 64 * Nx;  // 64 rows m'
  const u16* B1 = z1 + (size_t)bp * Gx * Nx;                           // 128 rows g
  auto STAGE1 = [&](int bufi, int k0) {
    char* base = smem + bufi * 12288;
    G2L16(A1 + (size_t)sar * Nx + k0 + sakg * 8, base + w * 1024);
    G2L16(B1 + (size_t)sbr0 * Nx + k0 + sbkg0 * 8, base + 4096 + w * 1024);
    G2L16(B1 + (size_t)sbr1 * Nx + k0 + sbkg1 * 8, base + 8192 + w * 1024);
  };

  v4f acc[2][4];
#pragma unroll
  for (int fr = 0; fr < 2; fr++)
#pragma unroll
    for (int fc = 0; fc < 4; fc++) acc[fr][fc] = (v4f){0.f, 0.f, 0.f, 0.f};

  STAGE1(0, 0);
  int cur = 0;
  for (int t = 0; t < 16; t++) {
    __syncthreads();
    if (t + 1 < 16) STAGE1(cur ^ 1, (t + 1) * 32);
    const char* bb = smem + cur * 12288;
    v8bf af[2], bf4[4];
#pragma unroll
    for (int fr = 0; fr < 2; fr++) af[fr] = *(const v8bf*)(bb + aoff[fr]);
#pragma unroll
    for (int fc = 0; fc < 4; fc++) bf4[fc] = *(const v8bf*)(bb + boff[fc]);
#pragma unroll
    for (int fr = 0; fr < 2; fr++)
#pragma unroll
      for (int fc = 0; fc < 4; fc++)
        acc[fr][fc] = __builtin_amdgcn_mfma_f32_16x16x32_bf16(af[fr], bf4[fc],
                                                              acc[fr][fc], 0, 0, 0);
    cur ^= 1;
  }

  // epilogue: C[m'loc][g] -> swizzled LDS tile (row 256B, XOR (row&7)<<4)
  {
    char* T = smem + OT;
#pragma unroll
    for (int fr = 0; fr < 2; fr++)
#pragma unroll
      for (int fc = 0; fc < 4; fc++) {
        int m0 = wr * 32 + fr * 16 + kslot * 4;
        int g = wc * 64 + fc * 16 + lr;
        v4f a = acc[fr][fc];
#pragma unroll
        for (int q = 0; q < 4; q++) {
          int row = m0 + q;
          *(u16*)(T + row * 256 + ((g * 2) ^ ((row & 7) << 4))) = f2b(a[q]);
        }
      }
  }
  __syncthreads();  // tile complete; staging free

  // ---------------- phase 2: filt ----------------
  const u16* A2s0 = xTb + (size_t)b * Nx * Gx + (size_t)rt * 64 * Gx;
  const u16* A2s1 = z1T + (size_t)bp * Nx * Gx + (size_t)rt * 64 * Gx;
  const u16* B2 = Hb + (size_t)p * Fx * (Kx * Gx);
  auto STAGE2 = [&](int bufi, int k0) {
    char* base = smem + bufi * 12288;
    if (k0 < 256) {
      const u16* Aseg = (k0 < 128) ? A2s0 : A2s1;
      int kin = k0 & 127;
      G2L16(Aseg + (size_t)sar * Gx + kin + sakg * 8, base + w * 1024);
    }
    G2L16(B2 + (size_t)sbr0 * (Kx * Gx) + k0 + sbkg0 * 8, base + 4096 + w * 1024);
    G2L16(B2 + (size_t)sbr1 * (Kx * Gx) + k0 + sbkg1 * 8, base + 8192 + w * 1024);
  };

  v4f acc2[2][4];
#pragma unroll
  for (int fr = 0; fr < 2; fr++)
#pragma unroll
    for (int fc = 0; fc < 4; fc++) acc2[fr][fc] = (v4f){0.f, 0.f, 0.f, 0.f};

  STAGE2(0, 0);
  cur = 0;
  for (int t = 0; t < 12; t++) {
    __syncthreads();
    if (t + 1 < 12) STAGE2(cur ^ 1, (t + 1) * 32);
    const char* bb = smem + cur * 12288;
    v8bf af[2], bf4[4];
    if (t < 8) {
#pragma unroll
      for (int fr = 0; fr < 2; fr++) af[fr] = *(const v8bf*)(bb + aoff[fr]);
    } else {
      const char* T = smem + OT;
      int tl = t - 8;
#pragma unroll
      for (int fr = 0; fr < 2; fr++) {
        int row = wr * 32 + fr * 16 + lr;
        af[fr] = *(const v8bf*)(T + row * 256 +
                                ((tl * 64 + kslot * 16) ^ ((row & 7) << 4)));
      }
    }
#pragma unroll
    for (int fc = 0; fc < 4; fc++) bf4[fc] = *(const v8bf*)(bb + boff[fc]);
#pragma unroll
    for (int fr = 0; fr < 2; fr++)
#pragma unroll
      for (int fc = 0; fc < 4; fc++)
        acc2[fr][fc] = __builtin_amdgcn_mfma_f32_16x16x32_bf16(af[fr], bf4[fc],
                                                               acc2[fr][fc], 0, 0, 0);
    cur ^= 1;
  }

  float* op = out + (size_t)(b * Px + p) * Fx * Nx;
#pragma unroll
  for (int fc = 0; fc < 4; fc++) {
    int f = wc * 64 + fc * 16 + lr;
    float bi = bias[f];
#pragma unroll
    for (int fr = 0; fr < 2; fr++) {
      int n0 = rt * 64 + wr * 32 + fr * 16 + kslot * 4;
      v4f a = acc2[fr][fc];
      float4 o;
      o.x = fmaxf(a[0] + bi, 0.f);
      o.y = fmaxf(a[1] + bi, 0.f);
      o.z = fmaxf(a[2] + bi, 0.f);
      o.w = fmaxf(a[3] + bi, 0.f);
      *(float4*)&op[(size_t)f * Nx + n0] = o;
    }
  }
}

// ---------------------------------------------------------------------------
extern "C" void kernel_launch(void* const* d_in, const int* in_sizes, int n_in,
                              void* d_out, int out_size, void* d_ws, size_t ws_size,
                              hipStream_t stream) {
  const float* x = (const float*)d_in[0];
  const float* S = (const float*)d_in[1];
  const float* W = (const float*)d_in[2];
  const float* h = (const float*)d_in[4];
  const float* bias = (const float*)d_in[5];
  float* out = (float*)d_out;

  char* ws = (char*)d_ws;
  u16* aijT  = (u16*)ws;                   // @ 0          33,554,432
  u16* WxT16 = (u16*)(ws + 33554432);      // @ 32M         8,388,608
  u16* xT16  = (u16*)(ws + 41943040);      // @ 40M         2,097,152
  u16* xTb   = (u16*)(ws + 44040192);      // @ 42M         2,097,152
  u16* xb    = (u16*)(ws + 46137344);      // @ 44M         2,097,152
  u16* z1    = (u16*)(ws + 48234496);      // @ 46M         8,388,608
  u16* z1T   = (u16*)(ws + 56623104);      // @ 54M         8,388,608
  u16* Hb    = (u16*)(ws + 73400320);      // @ 70M           393,216
  u16* W16   = (u16*)(ws + 73793536);      //                 131,072
  u32* mb    = (u32*)(ws + 73924608);      //                 524,288

  prep_kernel<<<dim3(1792), 256, 0, stream>>>(S, x, W, h, mb, xb, xTb, xT16, W16, Hb);
  wxt16_kernel<<<dim3(Bx * Px, Nx / 64), 256, 0, stream>>>(xT16, W16, WxT16);
  attn7_kernel<<<dim3(Bx * Px, Nx / 64), 512, 0, stream>>>(xT16, WxT16, mb, aijT);
  hop1_kernel<<<dim3(Bx * Px, 8), 256, 0, stream>>>(aijT, xb, z1, z1T);
  hop2filt_kernel<<<dim3(Bx * Px, 8), 256, 0, stream>>>(aijT, z1, z1T, xTb, Hb, bias, out);
  (void)in_sizes; (void)n_in; (void)out_size; (void)ws_size;
}

// Round 11
// 77.136 us; speedup vs baseline: 1.0090x; 1.0090x over previous
//
#include <hip/hip_runtime.h>

#define Bx 16
#define Gx 128
#define Nx 512
#define Px 4
#define Kx 3
#define Fx 128
#define NEG_SLOPE 0.2f
#define ZERO_TOL 1e-9f
#define BIGF 1.0e30f

typedef unsigned short u16;
typedef unsigned int u32;
typedef unsigned long long u64;
typedef __bf16 v8bf __attribute__((ext_vector_type(8)));
typedef _Float16 v8hf __attribute__((ext_vector_type(8)));
typedef float v4f __attribute__((ext_vector_type(4)));

__device__ __forceinline__ u16 f2b(float f) {
  union { float f; u32 u; } v; v.f = f;
  u32 r = (v.u + 0x7fffu + ((v.u >> 16) & 1u)) >> 16;
  return (u16)r;
}
__device__ __forceinline__ u16 f2h(float f) {
  union { _Float16 h; u16 u; } v; v.h = (_Float16)f;
  return v.u;
}

// async global->LDS, 16B per lane; LDS dst must be wave-uniform base (+lane*16)
#define G2L16(gsrc, ldst)                                                     \
  __builtin_amdgcn_global_load_lds(                                           \
      (const __attribute__((address_space(1))) void*)(gsrc),                  \
      (__attribute__((address_space(3))) void*)(ldst), 16, 0, 0)

// ---------------------------------------------------------------------------
// prep: fused {mask(ballot) | castx3 | castw16 | casth} by block range. (r10)
// ---------------------------------------------------------------------------
__global__ __launch_bounds__(256) void prep_kernel(const float* __restrict__ S,
                                                   const float* __restrict__ x,
                                                   const float* __restrict__ W,
                                                   const float* __restrict__ h,
                                                   u32* __restrict__ mb,
                                                   u16* __restrict__ xb,
                                                   u16* __restrict__ xTb,
                                                   u16* __restrict__ xT16,
                                                   u16* __restrict__ w16,
                                                   u16* __restrict__ Hb) {
  const int blk = blockIdx.x;
  const int tid = threadIdx.x;
  __shared__ float t[32][33];
  if (blk < 512) {
    const int w = tid >> 6, l = tid & 63;
    const size_t base = (size_t)blk * 8192;
#pragma unroll 4
    for (int i = 0; i < 32; i++) {
      float v = S[base + i * 256 + tid];
      u64 m = __ballot(fabsf(v) > ZERO_TOL);
      if (l == 0) *(u64*)&mb[(base + i * 256 + w * 64) >> 5] = m;
    }
  } else if (blk < 1536) {
    const int idx = blk - 512;
    const int b = idx >> 6, g0 = ((idx >> 4) & 3) * 32, n0 = (idx & 15) * 32;
    const int r = tid >> 3, c4 = (tid & 7) * 4;
    const float* xp = x + (size_t)b * Gx * Nx;
    float4 v = *(const float4*)&xp[(g0 + r) * Nx + n0 + c4];
    ushort4 o;
    o.x = f2b(v.x); o.y = f2b(v.y); o.z = f2b(v.z); o.w = f2b(v.w);
    *(ushort4*)&xb[(size_t)b * Gx * Nx + (g0 + r) * Nx + n0 + c4] = o;
    t[r][c4 + 0] = v.x; t[r][c4 + 1] = v.y; t[r][c4 + 2] = v.z; t[r][c4 + 3] = v.w;
    __syncthreads();
    float tv[4] = {t[c4 + 0][r], t[c4 + 1][r], t[c4 + 2][r], t[c4 + 3][r]};
    ushort4 ob, oh;
    ob.x = f2b(tv[0]); oh.x = f2h(tv[0]);
    ob.y = f2b(tv[1]); oh.y = f2h(tv[1]);
    ob.z = f2b(tv[2]); oh.z = f2h(tv[2]);
    ob.w = f2b(tv[3]); oh.w = f2h(tv[3]);
    size_t off = (size_t)b * Nx * Gx + (size_t)(n0 + r) * Gx + g0 + c4;
    *(ushort4*)&xTb[off] = ob;
    *(ushort4*)&xT16[off] = oh;
  } else if (blk < 1600) {
    int i4 = ((blk - 1536) * 256 + tid) * 4;
    float4 v = *(const float4*)&W[i4];
    ushort4 o;
    o.x = f2h(v.x); o.y = f2h(v.y); o.z = f2h(v.z); o.w = f2h(v.w);
    *(ushort4*)&w16[i4] = o;
  } else {
    int i4 = ((blk - 1600) * 256 + tid) * 4;
    float4 v = *(const float4*)&h[i4];
    ushort4 o;
    o.x = f2b(v.x); o.y = f2b(v.y); o.z = f2b(v.z); o.w = f2b(v.w);
    *(ushort4*)&Hb[i4] = o;
  }
}

// ---------------------------------------------------------------------------
// wxt16 (r6-verified, unchanged)
// ---------------------------------------------------------------------------
__global__ __launch_bounds__(256) void wxt16_kernel(const u16* __restrict__ xT16,
                                                    const u16* __restrict__ w16,
                                                    u16* __restrict__ WxT16) {
  __shared__ __align__(16) char smem[49152];
  constexpr int OB = 16384;
  const int bp = blockIdx.x, b = bp >> 2, p = bp & 3;
  const int rt = blockIdx.y;
  const int tid = threadIdx.x;
  const int w = tid >> 6, l = tid & 63;
  const int wr = w >> 1, wc = w & 1;
  const int lr = l & 15, ks = l >> 4;

  const u16* Ap = xT16 + ((size_t)b * Nx + rt * 64) * Gx;
  const u16* Bp = w16 + (size_t)p * Gx * Gx;
#pragma unroll
  for (int it = 0; it < 4; it++) {
    int chunk = it * 256 + w * 64 + l;
    int r = chunk >> 4, kq = l & 15;
    int kg = (kq ^ (r & 15)) * 8;
    G2L16(Ap + (size_t)r * Gx + kg, smem + it * 4096 + w * 1024);
  }
#pragma unroll
  for (int it = 0; it < 8; it++) {
    int chunk = it * 256 + w * 64 + l;
    int r = chunk >> 4, kq = l & 15;
    int kg = (kq ^ (r & 15)) * 8;
    G2L16(Bp + (size_t)r * Gx + kg, smem + OB + it * 4096 + w * 1024);
  }
  __syncthreads();

  v4f acc[2][4];
#pragma unroll
  for (int fr = 0; fr < 2; fr++)
#pragma unroll
    for (int fc = 0; fc < 4; fc++) acc[fr][fc] = (v4f){0.f, 0.f, 0.f, 0.f};

#pragma unroll
  for (int t = 0; t < 4; t++) {
    int kk = t * 4 + ks;
    v8hf ah[2];
#pragma unroll
    for (int fr = 0; fr < 2; fr++) {
      int ra = wr * 32 + fr * 16 + lr;
      ah[fr] = *(const v8hf*)(smem + ra * 256 + ((kk ^ (ra & 15)) * 16));
    }
#pragma unroll
    for (int fc = 0; fc < 4; fc++) {
      int rb = wc * 64 + fc * 16 + lr;
      v8hf bh = *(const v8hf*)(smem + OB + rb * 256 + ((kk ^ (rb & 15)) * 16));
#pragma unroll
      for (int fr = 0; fr < 2; fr++)
        acc[fr][fc] = __builtin_amdgcn_mfma_f32_16x16x32_f16(ah[fr], bh, acc[fr][fc], 0, 0, 0);
    }
  }

  u16* op = WxT16 + (size_t)bp * Nx * Gx;
#pragma unroll
  for (int fr = 0; fr < 2; fr++)
#pragma unroll
    for (int fc = 0; fc < 4; fc++) {
      int n = rt * 64 + wr * 32 + fr * 16 + ks * 4;
      int g = wc * 64 + fc * 16 + lr;
#pragma unroll
      for (int q = 0; q < 4; q++) op[(size_t)(n + q) * Gx + g] = f2h(acc[fr][fc][q]);
    }
}

// ---------------------------------------------------------------------------
// attn7 (r10, unchanged): A-in-regs, single 32KB B buffer, 4 blocks/CU.
// ---------------------------------------------------------------------------
__global__ __launch_bounds__(512, 4) void attn7_kernel(const u16* __restrict__ xT16,
                                                       const u16* __restrict__ WxT16,
                                                       const u32* __restrict__ mb,
                                                       u16* __restrict__ aijT) {
  __shared__ __align__(16) char smem[38912];
  constexpr int OMBS = 32768, ORED = 36864;
  const int bp = blockIdx.x, b = bp >> 2;
  const int i0 = blockIdx.y * 64;
  const int tid = threadIdx.x;
  const int w = tid >> 6, l = tid & 63;
  const int wr = w >> 2, wc = w & 3;
  const int lr = l & 15, ks = l >> 4;

  {
    const u32* mbp = mb + ((size_t)b * Nx + i0) * 16;
    u32* mbs = (u32*)(smem + OMBS);
    mbs[tid] = mbp[tid];
    mbs[tid + 512] = mbp[tid + 512];
  }
  {
    const u16* Ap = xT16 + ((size_t)b * Nx + i0) * Gx;
#pragma unroll
    for (int it = 0; it < 2; it++) {
      int chunk = it * 512 + w * 64 + l;
      int r = chunk >> 4, kq = l & 15;
      int kg = (kq ^ (r & 15)) * 8;
      G2L16(Ap + (size_t)r * Gx + kg, smem + it * 8192 + w * 1024);
    }
  }
  __syncthreads();

  v8hf areg[2][4];
#pragma unroll
  for (int fr = 0; fr < 2; fr++) {
    int ra = wr * 32 + fr * 16 + lr;
#pragma unroll
    for (int t = 0; t < 4; t++) {
      int kk = t * 4 + ks;
      areg[fr][t] = *(const v8hf*)(smem + ra * 256 + ((kk ^ (ra & 15)) * 16));
    }
  }
  __syncthreads();

  v4f acc[2][8];
#pragma unroll
  for (int fr = 0; fr < 2; fr++)
#pragma unroll
    for (int fc = 0; fc < 8; fc++) acc[fr][fc] = (v4f){0.f, 0.f, 0.f, 0.f};

  const u16* Bp = WxT16 + (size_t)bp * Nx * Gx;
  for (int t = 0; t < 4; t++) {
    int g0 = t * 32;
#pragma unroll
    for (int it = 0; it < 4; it++) {
      int chunk = it * 512 + w * 64 + l;
      int r = chunk >> 2, kq = l & 3;
      int kg = (kq ^ (r & 3)) * 8;
      G2L16(Bp + (size_t)r * Gx + g0 + kg, smem + it * 8192 + w * 1024);
    }
    __syncthreads();
#pragma unroll
    for (int fc = 0; fc < 8; fc++) {
      int rb = wc * 128 + fc * 16 + lr;
      v8hf bh = *(const v8hf*)(smem + rb * 64 + ((ks ^ (rb & 3)) * 16));
#pragma unroll
      for (int fr = 0; fr < 2; fr++)
        acc[fr][fc] = __builtin_amdgcn_mfma_f32_16x16x32_f16(areg[fr][t], bh, acc[fr][fc], 0, 0, 0);
    }
    __syncthreads();
  }

  u32* mbs = (u32*)(smem + OMBS);
  float* red0 = (float*)(smem + ORED);
  float* red1 = red0 + 256;

#pragma unroll
  for (int fr = 0; fr < 2; fr++)
#pragma unroll
    for (int q = 0; q < 4; q++) {
      int row = wr * 32 + fr * 16 + ks * 4 + q;
      float m = -BIGF;
#pragma unroll
      for (int fc = 0; fc < 8; fc++) {
        u32 word = mbs[row * 16 + wc * 4 + (fc >> 1)];
        int bit = ((fc & 1) << 4) + lr;
        float v = acc[fr][fc][q];
        v = v >= 0.f ? v : NEG_SLOPE * v;
        v = ((word >> bit) & 1u) ? v : -BIGF;
        acc[fr][fc][q] = v;
        m = fmaxf(m, v);
      }
      m = fmaxf(m, __shfl_xor(m, 1, 64));
      m = fmaxf(m, __shfl_xor(m, 2, 64));
      m = fmaxf(m, __shfl_xor(m, 4, 64));
      m = fmaxf(m, __shfl_xor(m, 8, 64));
      if (lr == 0) red0[row * 4 + wc] = m;
    }
  __syncthreads();
#pragma unroll
  for (int fr = 0; fr < 2; fr++)
#pragma unroll
    for (int q = 0; q < 4; q++) {
      int row = wr * 32 + fr * 16 + ks * 4 + q;
      float4 pm = *(const float4*)&red0[row * 4];
      float gm = fmaxf(fmaxf(pm.x, pm.y), fmaxf(pm.z, pm.w));
      float s = 0.f;
#pragma unroll
      for (int fc = 0; fc < 8; fc++) {
        float v = acc[fr][fc][q];
        float e = (v <= -0.5f * BIGF) ? 0.f : __expf(v - gm);
        acc[fr][fc][q] = e;
        s += e;
      }
      s += __shfl_xor(s, 1, 64);
      s += __shfl_xor(s, 2, 64);
      s += __shfl_xor(s, 4, 64);
      s += __shfl_xor(s, 8, 64);
      if (lr == 0) red1[row * 4 + wc] = s;
    }
  __syncthreads();
  u16* dst = aijT + (size_t)bp * Nx * Nx + i0;
#pragma unroll
  for (int fr = 0; fr < 2; fr++) {
    int rbase = wr * 32 + fr * 16 + ks * 4;
    float inv[4];
#pragma unroll
    for (int q = 0; q < 4; q++) {
      float4 ps = *(const float4*)&red1[(rbase + q) * 4];
      float tot = (ps.x + ps.y) + (ps.z + ps.w);
      inv[q] = tot > 0.f ? 1.f / tot : 0.f;
    }
#pragma unroll
    for (int fc = 0; fc < 8; fc++) {
      int j = wc * 128 + fc * 16 + lr;
      ushort4 pk;
      pk.x = f2b(acc[fr][fc][0] * inv[0]);
      pk.y = f2b(acc[fr][fc][1] * inv[1]);
      pk.z = f2b(acc[fr][fc][2] * inv[2]);
      pk.w = f2b(acc[fr][fc][3] * inv[3]);
      *(ushort4*)&dst[(size_t)j * Nx + rbase] = pk;
    }
  }
}

// ---------------------------------------------------------------------------
// hop1 @128x128 tile (m97 geometry): z1[g][m] = sum_n aijT[m][n]*xb[g][n].
// grid (B*P, 4), 256 thr (2x2 waves), 4x4 frags/wave, BK=32, dbuf 1-barrier.
// ---------------------------------------------------------------------------
__global__ __launch_bounds__(256) void hop1_kernel(const u16* __restrict__ pA,
                                                   const u16* __restrict__ pB,
                                                   u16* __restrict__ o1,
                                                   u16* __restrict__ o2) {
  __shared__ __align__(16) char smem[2][16384];  // A 8K | B 8K per buffer
  const int bp = blockIdx.x;
  const int b = bp >> 2;
  const int rt = blockIdx.y;  // m-tile of 128
  const int tid = threadIdx.x;
  const int w = tid >> 6, l = tid & 63;
  const int wr = w >> 1, wc = w & 1;
  const int lr = l & 15, kslot = l >> 4;

  const u16* Abase = pA + (size_t)bp * Nx * Nx + (size_t)rt * 128 * Nx;
  const u16* Bbase = pB + (size_t)b * Gx * Nx;

  const int sr = tid >> 2;                 // staging row 0..63 (and +64)
  const int skg = ((tid & 3) ^ (sr & 3)) * 8;

  int aoff[4], boff[4];
#pragma unroll
  for (int fr = 0; fr < 4; fr++) {
    int row = wr * 64 + fr * 16 + lr;
    aoff[fr] = row * 64 + ((kslot ^ (row & 3)) * 16);
  }
#pragma unroll
  for (int fc = 0; fc < 4; fc++) {
    int row = wc * 64 + fc * 16 + lr;
    boff[fc] = 8192 + row * 64 + ((kslot ^ (row & 3)) * 16);
  }

  auto STAGE = [&](int bufi, int k0) {
    char* base = smem[bufi];
    G2L16(Abase + (size_t)sr * Nx + k0 + skg, base + w * 1024);
    G2L16(Abase + (size_t)(sr + 64) * Nx + k0 + skg, base + 4096 + w * 1024);
    G2L16(Bbase + (size_t)sr * Nx + k0 + skg, base + 8192 + w * 1024);
    G2L16(Bbase + (size_t)(sr + 64) * Nx + k0 + skg, base + 12288 + w * 1024);
  };

  v4f acc[4][4];
#pragma unroll
  for (int fr = 0; fr < 4; fr++)
#pragma unroll
    for (int fc = 0; fc < 4; fc++) acc[fr][fc] = (v4f){0.f, 0.f, 0.f, 0.f};

  STAGE(0, 0);
  int cur = 0;
  for (int t = 0; t < 16; t++) {
    __syncthreads();
    if (t + 1 < 16) STAGE(cur ^ 1, (t + 1) * 32);
    const char* bb = smem[cur];
    v8bf af[4], bf4[4];
#pragma unroll
    for (int fr = 0; fr < 4; fr++) af[fr] = *(const v8bf*)(bb + aoff[fr]);
#pragma unroll
    for (int fc = 0; fc < 4; fc++) bf4[fc] = *(const v8bf*)(bb + boff[fc]);
#pragma unroll
    for (int fr = 0; fr < 4; fr++)
#pragma unroll
      for (int fc = 0; fc < 4; fc++)
        acc[fr][fc] = __builtin_amdgcn_mfma_f32_16x16x32_bf16(af[fr], bf4[fc],
                                                              acc[fr][fc], 0, 0, 0);
    cur ^= 1;
  }

  u16* z1p = o1 + (size_t)bp * Gx * Nx;
  u16* z1Tp = o2 + (size_t)bp * Nx * Gx;
#pragma unroll
  for (int fr = 0; fr < 4; fr++)
#pragma unroll
    for (int fc = 0; fc < 4; fc++) {
      int m0 = rt * 128 + wr * 64 + fr * 16 + kslot * 4;
      int g = wc * 64 + fc * 16 + lr;
      v4f a = acc[fr][fc];
      ushort4 pk;
      pk.x = f2b(a[0]); pk.y = f2b(a[1]); pk.z = f2b(a[2]); pk.w = f2b(a[3]);
      *(ushort4*)&z1p[(size_t)g * Nx + m0] = pk;
      z1Tp[(size_t)(m0 + 0) * Gx + g] = pk.x;
      z1Tp[(size_t)(m0 + 1) * Gx + g] = pk.y;
      z1Tp[(size_t)(m0 + 2) * Gx + g] = pk.z;
      z1Tp[(size_t)(m0 + 3) * Gx + g] = pk.w;
    }
}

// ---------------------------------------------------------------------------
// hop2filt @128 tiles: phase1 z2tile[m'][g] (128x128 -> swizzled LDS),
// phase2 out[f][n=m'] with A={xTb,z1T,tile} (K=384), B=Hb. grid (B*P,4).
// ---------------------------------------------------------------------------
__global__ __launch_bounds__(256) void hop2filt_kernel(const u16* __restrict__ aijT,
                                                       const u16* __restrict__ z1,
                                                       const u16* __restrict__ z1T,
                                                       const u16* __restrict__ xTb,
                                                       const u16* __restrict__ Hb,
                                                       const float* __restrict__ bias,
                                                       float* __restrict__ out) {
  __shared__ __align__(16) char smem[65536];  // 2x16K staging | 32K z2 tile
  constexpr int OT = 32768;
  const int bp = blockIdx.x, b = bp >> 2, p = bp & 3;
  const int rt = blockIdx.y;  // m'-tile of 128
  const int tid = threadIdx.x;
  const int w = tid >> 6, l = tid & 63;
  const int wr = w >> 1, wc = w & 1;
  const int lr = l & 15, kslot = l >> 4;

  const int sr = tid >> 2;
  const int skg = ((tid & 3) ^ (sr & 3)) * 8;

  int aoff[4], boff[4];
#pragma unroll
  for (int fr = 0; fr < 4; fr++) {
    int row = wr * 64 + fr * 16 + lr;
    aoff[fr] = row * 64 + ((kslot ^ (row & 3)) * 16);
  }
#pragma unroll
  for (int fc = 0; fc < 4; fc++) {
    int row = wc * 64 + fc * 16 + lr;
    boff[fc] = 8192 + row * 64 + ((kslot ^ (row & 3)) * 16);
  }

  // ---------------- phase 1: z2 tile (A=aijT m' rows, B=z1 g rows) ---------
  const u16* A1 = aijT + (size_t)bp * Nx * Nx + (size_t)rt * 128 * Nx;
  const u16* B1 = z1 + (size_t)bp * Gx * Nx;
  auto STAGE1 = [&](int bufi, int k0) {
    char* base = smem + bufi * 16384;
    G2L16(A1 + (size_t)sr * Nx + k0 + skg, base + w * 1024);
    G2L16(A1 + (size_t)(sr + 64) * Nx + k0 + skg, base + 4096 + w * 1024);
    G2L16(B1 + (size_t)sr * Nx + k0 + skg, base + 8192 + w * 1024);
    G2L16(B1 + (size_t)(sr + 64) * Nx + k0 + skg, base + 12288 + w * 1024);
  };

  v4f acc[4][4];
#pragma unroll
  for (int fr = 0; fr < 4; fr++)
#pragma unroll
    for (int fc = 0; fc < 4; fc++) acc[fr][fc] = (v4f){0.f, 0.f, 0.f, 0.f};

  STAGE1(0, 0);
  int cur = 0;
  for (int t = 0; t < 16; t++) {
    __syncthreads();
    if (t + 1 < 16) STAGE1(cur ^ 1, (t + 1) * 32);
    const char* bb = smem + cur * 16384;
    v8bf af[4], bf4[4];
#pragma unroll
    for (int fr = 0; fr < 4; fr++) af[fr] = *(const v8bf*)(bb + aoff[fr]);
#pragma unroll
    for (int fc = 0; fc < 4; fc++) bf4[fc] = *(const v8bf*)(bb + boff[fc]);
#pragma unroll
    for (int fr = 0; fr < 4; fr++)
#pragma unroll
      for (int fc = 0; fc < 4; fc++)
        acc[fr][fc] = __builtin_amdgcn_mfma_f32_16x16x32_bf16(af[fr], bf4[fc],
                                                              acc[fr][fc], 0, 0, 0);
    cur ^= 1;
  }

  // epilogue: tile[row=m'loc][col=g], row 256B, XOR ((row&7)<<4)
  {
    char* T = smem + OT;
#pragma unroll
    for (int fr = 0; fr < 4; fr++)
#pragma unroll
      for (int fc = 0; fc < 4; fc++) {
        int m0 = wr * 64 + fr * 16 + kslot * 4;
        int g = wc * 64 + fc * 16 + lr;
        v4f a = acc[fr][fc];
#pragma unroll
        for (int q = 0; q < 4; q++) {
          int row = m0 + q;
          *(u16*)(T + row * 256 + ((g * 2) ^ ((row & 7) << 4))) = f2b(a[q]);
        }
      }
  }

  // ---------------- phase 2: filt (A={xTb,z1T,tile}, B=Hb) -----------------
  const u16* A2s0 = xTb + (size_t)b * Nx * Gx + (size_t)rt * 128 * Gx;
  const u16* A2s1 = z1T + (size_t)bp * Nx * Gx + (size_t)rt * 128 * Gx;
  const u16* B2 = Hb + (size_t)p * Fx * (Kx * Gx);
  auto STAGE2 = [&](int bufi, int k0) {
    char* base = smem + bufi * 16384;
    if (k0 < 256) {
      const u16* Aseg = (k0 < 128) ? A2s0 : A2s1;
      int kin = k0 & 127;
      G2L16(Aseg + (size_t)sr * Gx + kin + skg, base + w * 1024);
      G2L16(Aseg + (size_t)(sr + 64) * Gx + kin + skg, base + 4096 + w * 1024);
    }
    G2L16(B2 + (size_t)sr * (Kx * Gx) + k0 + skg, base + 8192 + w * 1024);
    G2L16(B2 + (size_t)(sr + 64) * (Kx * Gx) + k0 + skg, base + 12288 + w * 1024);
  };

  v4f acc2[4][4];
#pragma unroll
  for (int fr = 0; fr < 4; fr++)
#pragma unroll
    for (int fc = 0; fc < 4; fc++) acc2[fr][fc] = (v4f){0.f, 0.f, 0.f, 0.f};

  STAGE2(0, 0);
  cur = 0;
  for (int t = 0; t < 12; t++) {
    __syncthreads();
    if (t + 1 < 12) STAGE2(cur ^ 1, (t + 1) * 32);
    const char* bb = smem + cur * 16384;
    v8bf af[4], bf4[4];
    if (t < 8) {
#pragma unroll
      for (int fr = 0; fr < 4; fr++) af[fr] = *(const v8bf*)(bb + aoff[fr]);
    } else {
      const char* T = smem + OT;
      int tl = t - 8;
#pragma unroll
      for (int fr = 0; fr < 4; fr++) {
        int row = wr * 64 + fr * 16 + lr;
        af[fr] = *(const v8bf*)(T + row * 256 +
                                (((tl * 4 + kslot) * 16) ^ ((row & 7) << 4)));
      }
    }
#pragma unroll
    for (int fc = 0; fc < 4; fc++) bf4[fc] = *(const v8bf*)(bb + boff[fc]);
#pragma unroll
    for (int fr = 0; fr < 4; fr++)
#pragma unroll
      for (int fc = 0; fc < 4; fc++)
        acc2[fr][fc] = __builtin_amdgcn_mfma_f32_16x16x32_bf16(af[fr], bf4[fc],
                                                               acc2[fr][fc], 0, 0, 0);
    cur ^= 1;
  }

  float* op = out + (size_t)(b * Px + p) * Fx * Nx;
#pragma unroll
  for (int fc = 0; fc < 4; fc++) {
    int f = wc * 64 + fc * 16 + lr;
    float bi = bias[f];
#pragma unroll
    for (int fr = 0; fr < 4; fr++) {
      int n0 = rt * 128 + wr * 64 + fr * 16 + kslot * 4;
      v4f a = acc2[fr][fc];
      float4 o;
      o.x = fmaxf(a[0] + bi, 0.f);
      o.y = fmaxf(a[1] + bi, 0.f);
      o.z = fmaxf(a[2] + bi, 0.f);
      o.w = fmaxf(a[3] + bi, 0.f);
      *(float4*)&op[(size_t)f * Nx + n0] = o;
    }
  }
}

// ---------------------------------------------------------------------------
extern "C" void kernel_launch(void* const* d_in, const int* in_sizes, int n_in,
                              void* d_out, int out_size, void* d_ws, size_t ws_size,
                              hipStream_t stream) {
  const float* x = (const float*)d_in[0];
  const float* S = (const float*)d_in[1];
  const float* W = (const float*)d_in[2];
  const float* h = (const float*)d_in[4];
  const float* bias = (const float*)d_in[5];
  float* out = (float*)d_out;

  char* ws = (char*)d_ws;
  u16* aijT  = (u16*)ws;                   // @ 0          33,554,432
  u16* WxT16 = (u16*)(ws + 33554432);      // @ 32M         8,388,608
  u16* xT16  = (u16*)(ws + 41943040);      // @ 40M         2,097,152
  u16* xTb   = (u16*)(ws + 44040192);      // @ 42M         2,097,152
  u16* xb    = (u16*)(ws + 46137344);      // @ 44M         2,097,152
  u16* z1    = (u16*)(ws + 48234496);      // @ 46M         8,388,608
  u16* z1T   = (u16*)(ws + 56623104);      // @ 54M         8,388,608
  u16* Hb    = (u16*)(ws + 73400320);      // @ 70M           393,216
  u16* W16   = (u16*)(ws + 73793536);      //                 131,072
  u32* mb    = (u32*)(ws + 73924608);      //                 524,288

  prep_kernel<<<dim3(1792), 256, 0, stream>>>(S, x, W, h, mb, xb, xTb, xT16, W16, Hb);
  wxt16_kernel<<<dim3(Bx * Px, Nx / 64), 256, 0, stream>>>(xT16, W16, WxT16);
  attn7_kernel<<<dim3(Bx * Px, Nx / 64), 512, 0, stream>>>(xT16, WxT16, mb, aijT);
  hop1_kernel<<<dim3(Bx * Px, 4), 256, 0, stream>>>(aijT, xb, z1, z1T);
  hop2filt_kernel<<<dim3(Bx * Px, 4), 256, 0, stream>>>(aijT, z1, z1T, xTb, Hb, bias, out);
  (void)in_sizes; (void)n_in; (void)out_size; (void)ws_size;
}